// Round 4
// baseline (117.828 us; speedup 1.0000x reference)
//
#include <hip/hip_runtime.h>
#include <hip/hip_bf16.h>

// Edge MLP via MFMA, round 4: occupancy + memory-level-parallelism restructure.
//  - 1 M-tile (16 edges) per wave -> acc shrinks 64->16 regs; __launch_bounds__(256,5)
//    targets 5 waves/SIMD resident (round-3 was ~2: 112 VGPR + 64 AGPR unified).
//  - Explicit rolling gather pipeline: S/D row loads issued ~2 ks-steps ahead.
//  - Single fused prep kernel (h->bf16 table + W1->W1^T bf16 in d_ws).
//  - B-frags from global W1^T (16 KB, L1-resident). No LDS, no __syncthreads.
//  - Grid 9375 blocks exactly (600000 = 9375 * 4 waves * 16 edges), zero tail.

#define NEDGE 600000
#define NNODES 50000
#define DIN 128
#define DH 64
#define HBLOCKS ((NNODES * DIN) / (256 * 4))   // 6250
#define WBLOCKS ((DIN * DH) / (256 * 4))       // 8

typedef __attribute__((ext_vector_type(8))) short bf16x8;
typedef __attribute__((ext_vector_type(4))) float f32x4;
typedef __attribute__((ext_vector_type(4))) unsigned int u32x4;

static __device__ __forceinline__ short f2bf(float f) {
    __hip_bfloat16 hb = __float2bfloat16(f);
    return *reinterpret_cast<short*>(&hb);
}
static __device__ __forceinline__ float bflo(unsigned int w) {
    return __builtin_bit_cast(float, w << 16);
}
static __device__ __forceinline__ float bfhi(unsigned int w) {
    return __builtin_bit_cast(float, w & 0xffff0000u);
}

// ---- fused prep. wofs: block index where the W1^T part starts (h part = [0,wofs)).
__global__ __launch_bounds__(256) void prep_kernel(
    const float* __restrict__ h, const float* __restrict__ W1,
    unsigned short* __restrict__ hbf, unsigned short* __restrict__ w1t, int wofs)
{
    int b = blockIdx.x;
    if (b < wofs) {
        int i = (b * 256 + threadIdx.x) * 4;
        f32x4 v = *reinterpret_cast<const f32x4*>(h + i);
        ushort4 o;
        o.x = (unsigned short)f2bf(v[0]);
        o.y = (unsigned short)f2bf(v[1]);
        o.z = (unsigned short)f2bf(v[2]);
        o.w = (unsigned short)f2bf(v[3]);
        *reinterpret_cast<ushort4*>(hbf + i) = o;
    } else {
        int j = ((b - wofs) * 256 + threadIdx.x) * 4;   // 0..8191
        f32x4 w = *reinterpret_cast<const f32x4*>(W1 + j);
        int k = j >> 6, c = j & 63;
#pragma unroll
        for (int q = 0; q < 4; ++q)
            w1t[(c + q) * DIN + k] = (unsigned short)f2bf(w[q]);
    }
}

// ---- main: per wave C[16 edges][64 hid] = 4 ks x 4 n mfma_f32_16x16x32_bf16 ----
template<bool BF>
__global__ __launch_bounds__(256, 5) void mlp_edge_v4(
    const unsigned short* __restrict__ hbf,   // BF path gather table
    const float* __restrict__ hf,             // fp32 fallback gather
    const unsigned short* __restrict__ w1t,
    const float* __restrict__ b1,
    const float* __restrict__ W2,
    const float* __restrict__ b2,
    const int* __restrict__ src,
    const int* __restrict__ dst,
    float* __restrict__ out)
{
    const int tid = threadIdx.x;
    const int l = tid & 63;
    const int lr = l & 15;   // edge-within-tile (A rows) / hid-col (B/C cols)
    const int g = l >> 4;    // k-group (8 elems)
    const int wbase = blockIdx.x * 64 + (tid >> 6) * 16;   // 16 edges/wave

    const unsigned e = (unsigned)(wbase + lr);
    const unsigned sa = (unsigned)src[e] * (unsigned)DIN;  // element offsets
    const unsigned da = (unsigned)dst[e] * (unsigned)DIN;

    f32x4 acc[4];
#pragma unroll
    for (int n = 0; n < 4; ++n) {
        float bv = b1[n * 16 + lr];
        acc[n] = (f32x4){bv, bv, bv, bv};
    }

    bf16x8 B[4];
    const unsigned kg = (unsigned)(g * 8);

    if constexpr (BF) {
        const unsigned short* __restrict__ p = hbf;
        // issue first 6 of 8 gather loads up front (rolling window)
        u32x4 S0 = *reinterpret_cast<const u32x4*>(p + sa + kg);
        u32x4 D0 = *reinterpret_cast<const u32x4*>(p + da + kg);
        u32x4 S1 = *reinterpret_cast<const u32x4*>(p + sa + 32 + kg);
        u32x4 D1 = *reinterpret_cast<const u32x4*>(p + da + 32 + kg);
        u32x4 S2 = *reinterpret_cast<const u32x4*>(p + sa + 64 + kg);
        u32x4 D2 = *reinterpret_cast<const u32x4*>(p + da + 64 + kg);

#pragma unroll
        for (int ks = 0; ks < 4; ++ks) {
            u32x4 S = (ks == 0) ? S0 : (ks == 1) ? S1 : (ks == 2) ? S2
                    : *reinterpret_cast<const u32x4*>(p + sa + 96 + kg);
            u32x4 D = (ks == 0) ? D0 : (ks == 1) ? D1 : (ks == 2) ? D2
                    : *reinterpret_cast<const u32x4*>(p + da + 96 + kg);
#pragma unroll
            for (int n = 0; n < 4; ++n)
                B[n] = *reinterpret_cast<const bf16x8*>(w1t + (n * 16 + lr) * DIN + ks * 32 + kg);
            bf16x8 A;
#pragma unroll
            for (int w = 0; w < 4; ++w) {
                A[2 * w]     = f2bf(bflo(S[w]) * bflo(D[w]));
                A[2 * w + 1] = f2bf(bfhi(S[w]) * bfhi(D[w]));
            }
#pragma unroll
            for (int n = 0; n < 4; ++n)
                acc[n] = __builtin_amdgcn_mfma_f32_16x16x32_bf16(A, B[n], acc[n], 0, 0, 0);
        }
    } else {
#pragma unroll
        for (int ks = 0; ks < 4; ++ks) {
            const float* ps = hf + sa + ks * 128 + g * 32;
            const float* pd = hf + da + ks * 128 + g * 32;
            f32x4 s0 = *reinterpret_cast<const f32x4*>(ps);
            f32x4 s1 = *reinterpret_cast<const f32x4*>(ps + 4);
            f32x4 d0 = *reinterpret_cast<const f32x4*>(pd);
            f32x4 d1 = *reinterpret_cast<const f32x4*>(pd + 4);
#pragma unroll
            for (int n = 0; n < 4; ++n)
                B[n] = *reinterpret_cast<const bf16x8*>(w1t + (n * 16 + lr) * DIN + ks * 32 + kg);
            bf16x8 A;
#pragma unroll
            for (int q = 0; q < 4; ++q) {
                A[q]     = f2bf(s0[q] * d0[q]);
                A[q + 4] = f2bf(s1[q] * d1[q]);
            }
#pragma unroll
            for (int n = 0; n < 4; ++n)
                acc[n] = __builtin_amdgcn_mfma_f32_16x16x32_bf16(A, B[n], acc[n], 0, 0, 0);
        }
    }

    // ---- layer 2: relu + [64]->[2], 16-lane butterfly reduce ----
    float w2v[4][2];
#pragma unroll
    for (int n = 0; n < 4; ++n) {
        float2 w = *reinterpret_cast<const float2*>(W2 + (n * 16 + lr) * 2);
        w2v[n][0] = w.x; w2v[n][1] = w.y;
    }
    const float bb0 = b2[0], bb1 = b2[1];

    float o0 = 0.f, o1 = 0.f;
#pragma unroll
    for (int r = 0; r < 4; ++r) {
        float p0 = 0.f, p1 = 0.f;
#pragma unroll
        for (int n = 0; n < 4; ++n) {
            float v = fmaxf(acc[n][r], 0.f);
            p0 = fmaf(v, w2v[n][0], p0);
            p1 = fmaf(v, w2v[n][1], p1);
        }
#pragma unroll
        for (int sh = 1; sh < 16; sh <<= 1) {
            p0 += __shfl_xor(p0, sh, 64);
            p1 += __shfl_xor(p1, sh, 64);
        }
        if (lr == r) { o0 = p0; o1 = p1; }
    }
    if (lr < 4) {                       // C row = g*4 + reg -> edge wbase + g*4 + lr
        int edge = wbase + g * 4 + lr;
        float2 ov = make_float2(o0 + bb0, o1 + bb1);
        *reinterpret_cast<float2*>(out + (size_t)edge * 2) = ov;
    }
}

extern "C" void kernel_launch(void* const* d_in, const int* in_sizes, int n_in,
                              void* d_out, int out_size, void* d_ws, size_t ws_size,
                              hipStream_t stream) {
    const float* h  = (const float*)d_in[0];
    const float* W1 = (const float*)d_in[1];
    const float* b1 = (const float*)d_in[2];
    const float* W2 = (const float*)d_in[3];
    const float* b2 = (const float*)d_in[4];
    const int* src  = (const int*)d_in[5];
    const int* dst  = (const int*)d_in[6];
    float* out = (float*)d_out;

    const int blocks = NEDGE / 64;   // 9375
    const size_t hbytes = (size_t)NNODES * DIN * 2;   // 12.8 MB
    const size_t wbytes = (size_t)DH * DIN * 2;       // 16 KB

    if (ws_size >= hbytes + wbytes) {
        unsigned short* hbf = (unsigned short*)d_ws;
        unsigned short* w1t = hbf + (size_t)NNODES * DIN;
        prep_kernel<<<HBLOCKS + WBLOCKS, 256, 0, stream>>>(h, W1, hbf, w1t, HBLOCKS);
        mlp_edge_v4<true><<<blocks, 256, 0, stream>>>(hbf, nullptr, w1t, b1, W2, b2, src, dst, out);
    } else if (ws_size >= wbytes) {
        unsigned short* w1t = (unsigned short*)d_ws;
        prep_kernel<<<WBLOCKS, 256, 0, stream>>>(h, W1, nullptr, w1t, 0);  // all blocks take W1 branch
        mlp_edge_v4<false><<<blocks, 256, 0, stream>>>(nullptr, h, w1t, b1, W2, b2, src, dst, out);
    }
}